// Round 18
// baseline (189.856 us; speedup 1.0000x reference)
//
#include <hip/hip_runtime.h>
#include <hip/hip_bf16.h>
#include <stdint.h>

// Correlation (FlowNet), md=4: out[b, di*9+dj, h, w] = sum_c x[b,c,h,w]*yp[b,c,h+di-4,w+dj-4] / 256
// R17 = R9 champion + load-early pipeline, correctly register-budgeted:
//  - launch_bounds(512,3): ~170 unified regs/lane -> 24 held-load VGPRs fit (R12's
//    spill was the (512,4)=128-reg cap, not the mechanism).
//  - y loads for chunk t+1 issued BEFORE compute(t); cvt after compute -> vmcnt
//    wait is one full compute phase downstream (kills the burst-drain stall).
//  - x staged via global_load_lds DMA (f32, dbuf 2x16KB): zero staging VGPRs,
//    A-frags = 8 ds_read_b32 + cvt per chunk per wave.
//  - y LDS single-buffer 32KB, R9 tr16 subtile path verbatim. LDS total 64KB.

using f32x4 = __attribute__((ext_vector_type(4))) float;
using s16x4 = __attribute__((ext_vector_type(4))) short;
using u16x4 = __attribute__((ext_vector_type(4))) unsigned short;

#define AS1 __attribute__((address_space(1)))
#define AS3 __attribute__((address_space(3)))

#define C_DIM 256
#define H_DIM 96
#define W_DIM 192
#define HWSZ  (H_DIM * W_DIM)
#define MD 4
#define KD 9
#define CHUNK 32
#define NCHUNK 8
#define HR 8
#define NTHR 512
#define WTILES 12          // 192/16
#define HQ 12              // 96/8
#define SUB_B 128          // [4c][16s] bf16 subtile = 128B, aligned (tr native)
#define YROW_B (16 * SUB_B)   // 2048B per y row (2 s-tiles x 8 cg)
#define YBYTES (16 * YROW_B)  // 32768, single buffer
#define XBUF_B 16384          // x f32: 8r x 32c x 16w x 4B, double-buffered
#define LDS_BYTES (YBYTES + 2 * XBUF_B)  // 65536

static __device__ __forceinline__ unsigned short bf16b(float f) {
  __bf16 h = (__bf16)f;                   // RNE
  unsigned short s; __builtin_memcpy(&s, &h, 2); return s;
}

// per-lane: reads column (l&15) of the [4c][16s] bf16 subtile at its address
static __device__ __forceinline__ s16x4 tr16(uint32_t addr) {
  s16x4 d;
  asm volatile("ds_read_b64_tr_b16 %0, %1" : "=v"(d) : "v"(addr));
  return d;
}

__global__ __launch_bounds__(NTHR, 3)
void corr_mfma(const float* __restrict__ xg, const float* __restrict__ yg,
               float* __restrict__ outg) {
  __shared__ __align__(16) char smem[LDS_BYTES];

  const int bid = blockIdx.x;             // 1152 = 8 * 144
  const int b   = bid & 7;                // batch == XCD (round-robin dispatch)
  const int rem = bid >> 3;               // hq fastest -> h-halo L2 reuse (R9 order)
  const int wt  = rem / HQ;
  const int hq  = rem - wt * HQ;
  const int w0  = wt * 16;
  const int h0  = hq * HR;

  const int tid  = threadIdx.x;
  const int lane = tid & 63;
  const int wv   = tid >> 6;              // wave id 0..7 -> output row h0+wv
  const int hi   = lane >> 4;
  const int lm   = lane & 15;

  const uint32_t sbase = (uint32_t)(uintptr_t)&smem[0];

  // ---- y staging decode (R9 verbatim): 3072 quads = 6 per thread
  uint32_t goffY[6], loffY[6];
  uint32_t vmY = 0;
#pragma unroll
  for (int i = 0; i < 6; ++i) {
    const int qid = i * NTHR + tid;
    const int q = qid % 6;
    const int c = (qid / 6) % CHUNK;
    const int r = qid / 192;              // y row 0..15 -> h0+r-4
    const int hg = h0 + r - MD;
    const int sg = w0 - MD + 4 * q;       // 4-aligned -> OOB is whole-quad only
    const bool ok = (hg >= 0) && (hg < H_DIM) && (sg >= 0) && (sg < W_DIM);
    if (ok) vmY |= (1u << i);
    goffY[i] = ok ? (uint32_t)(((b * C_DIM + c) * H_DIM + hg) * W_DIM + sg) : 0u;
    const int s = 4 * q;
    loffY[i] = r * YROW_B + (s >> 4) * (8 * SUB_B) + (c >> 2) * SUB_B
             + (c & 3) * 32 + (s & 15) * 2;
  }

  // ---- x DMA decode: 1024 16B-units/chunk, 2 instrs/thread.
  // unit = j*512+tid -> (r = u/128, c = (u%128)/4, sq = u%4); LDS dword = u*4+e
  // = r*512 + c*16 + sq*4 + e  => X layout [r][c][w], w-stride 1.
  uint32_t goffX[2];
#pragma unroll
  for (int j = 0; j < 2; ++j) {
    const int u = j * NTHR + tid;
    const int r = u >> 7;
    const int c = (u >> 2) & 31;
    const int sq = u & 3;
    goffX[j] = (uint32_t)(((b * C_DIM + c) * H_DIM + (h0 + r)) * W_DIM + (w0 + 4 * sq));
  }

  f32x4 acc[KD][2];
#pragma unroll
  for (int di = 0; di < KD; ++di) {
    acc[di][0] = f32x4{0.f, 0.f, 0.f, 0.f};
    acc[di][1] = f32x4{0.f, 0.f, 0.f, 0.f};
  }

  const uint32_t bbase = sbase + wv * YROW_B + hi * SUB_B + lm * 8;
  // A-read (f32 LDS): dword = wv*512 + (kh*16 + 4hi + e)*16 + lm
  const int abase = wv * 512 + hi * 64 + lm;

  AS3 char* lds = (AS3 char*)smem;

#define XDMA(t) { \
    const uint32_t co = (uint32_t)(t) * CHUNK * HWSZ; \
    const uint32_t dst = YBYTES + (uint32_t)((t) & 1) * XBUF_B; \
    _Pragma("unroll") \
    for (int j = 0; j < 2; ++j) \
      __builtin_amdgcn_global_load_lds((const AS1 void*)(xg + goffX[j] + co), \
          (AS3 void*)(lds + dst + (uint32_t)(j * 8 + wv) * 1024), 16, 0, 0); \
  }

#define YLOAD(t) { \
    const uint32_t co = (uint32_t)(t) * CHUNK * HWSZ; \
    _Pragma("unroll") \
    for (int i = 0; i < 6; ++i) { \
      float4 v4 = make_float4(0.f, 0.f, 0.f, 0.f); \
      if (vmY & (1u << i)) v4 = *(const float4*)(yg + goffY[i] + co); \
      yv[i] = v4; \
    } }

  float4 yv[6];

  // ---- prologue: y(0)+xDMA(0); cvt+write y(0); issue y(1)+xDMA(1); publish
  XDMA(0)
  YLOAD(0)
#pragma unroll
  for (int i = 0; i < 6; ++i)
    *(u16x4*)(smem + loffY[i]) =
        u16x4{bf16b(yv[i].x), bf16b(yv[i].y), bf16b(yv[i].z), bf16b(yv[i].w)};
  XDMA(1)
  YLOAD(1)
  __syncthreads();                        // drains xDMA(0); publishes y(0)

  for (int t = 0; t < NCHUNK; ++t) {
    // ---- compute chunk t: A from X f32 buf[t&1] (8 b32+cvt), B via tr16 (R9)
    const float* X = (const float*)(smem + YBYTES + (t & 1) * XBUF_B);
    s16x4 afr0, afr1;
    {
      float a0 = X[abase],       a1 = X[abase + 16];
      float a2 = X[abase + 32],  a3 = X[abase + 48];
      float a4 = X[abase + 256], a5 = X[abase + 272];
      float a6 = X[abase + 288], a7 = X[abase + 304];
      afr0[0] = (short)bf16b(a0); afr0[1] = (short)bf16b(a1);
      afr0[2] = (short)bf16b(a2); afr0[3] = (short)bf16b(a3);
      afr1[0] = (short)bf16b(a4); afr1[1] = (short)bf16b(a5);
      afr1[2] = (short)bf16b(a6); afr1[3] = (short)bf16b(a7);
    }
    s16x4 bc0 = tr16(bbase);
    s16x4 bc1 = tr16(bbase + 4 * SUB_B);
    s16x4 bc2 = tr16(bbase + 8 * SUB_B);
    s16x4 bc3 = tr16(bbase + 12 * SUB_B);
#pragma unroll
    for (int di = 0; di < KD; ++di) {
      s16x4 bn0, bn1, bn2, bn3;
      if (di < 8) {
        const uint32_t bb = bbase + (uint32_t)(di + 1) * YROW_B;
        bn0 = tr16(bb);
        bn1 = tr16(bb + 4 * SUB_B);
        bn2 = tr16(bb + 8 * SUB_B);
        bn3 = tr16(bb + 12 * SUB_B);
        asm volatile("s_waitcnt lgkmcnt(4)" ::: "memory");
      } else {
        asm volatile("s_waitcnt lgkmcnt(0)" ::: "memory");
      }
      __builtin_amdgcn_sched_barrier(0);  // rule #18
      acc[di][0] = __builtin_amdgcn_mfma_f32_16x16x16bf16_1k(afr0, bc0, acc[di][0], 0, 0, 0);
      acc[di][0] = __builtin_amdgcn_mfma_f32_16x16x16bf16_1k(afr1, bc1, acc[di][0], 0, 0, 0);
      acc[di][1] = __builtin_amdgcn_mfma_f32_16x16x16bf16_1k(afr0, bc2, acc[di][1], 0, 0, 0);
      acc[di][1] = __builtin_amdgcn_mfma_f32_16x16x16bf16_1k(afr1, bc3, acc[di][1], 0, 0, 0);
      if (di < 8) { bc0 = bn0; bc1 = bn1; bc2 = bn2; bc3 = bn3; }
    }

    // ---- barrier 1: all waves past compute(t) (y reads done); y(t+1) vmcnt
    // drains here too -- a full compute phase after issue.
    __syncthreads();

    if (t + 1 < NCHUNK) {
      // cvt + write y(t+1) into the single y buffer
#pragma unroll
      for (int i = 0; i < 6; ++i)
        *(u16x4*)(smem + loffY[i]) =
            u16x4{bf16b(yv[i].x), bf16b(yv[i].y), bf16b(yv[i].z), bf16b(yv[i].w)};
      // issue y(t+2) loads + x-DMA(t+2) (drain one full compute phase away)
      if (t + 2 < NCHUNK) {
        XDMA(t + 2)                       // dest buf[t&1]: its reads finished above
        YLOAD(t + 2)
      }
    }
    // ---- barrier 2: publish y(t+1) writes
    __syncthreads();
  }

  // ---- epilogue (R9 verbatim): D[m][n]: n=lm, m=hi*4+rg. dj = t*16 + lm - m.
  const int h = h0 + wv;
  const float scale = 1.f / 256.f;
#pragma unroll
  for (int di = 0; di < KD; ++di) {
#pragma unroll
    for (int t = 0; t < 2; ++t) {
#pragma unroll
      for (int rg = 0; rg < 4; ++rg) {
        const int m = hi * 4 + rg;
        const int dj = t * 16 + lm - m;
        if (0 <= dj && dj <= 8) {
          outg[((b * (KD * KD) + di * KD + dj) * H_DIM + h) * W_DIM + w0 + m] =
              acc[di][t][rg] * scale;
        }
      }
    }
  }
}

extern "C" void kernel_launch(void* const* d_in, const int* in_sizes, int n_in,
                              void* d_out, int out_size, void* d_ws, size_t ws_size,
                              hipStream_t stream) {
  const float* x = (const float*)d_in[0];
  const float* y = (const float*)d_in[1];
  float* out = (float*)d_out;
  (void)in_sizes; (void)n_in; (void)d_ws; (void)ws_size; (void)out_size;

  const int grid = 8 * HQ * WTILES;       // 1152 blocks, 512 threads
  corr_mfma<<<dim3(grid), dim3(NTHR), 0, stream>>>(x, y, out);
}